// Round 7
// baseline (226.917 us; speedup 1.0000x reference)
//
#include <hip/hip_runtime.h>
#include <hip/hip_bf16.h>
#include <math.h>

// Problem constants (from reference setup_inputs)
#define BATCH 8
#define SEQ   1536
#define DIM   1024
#define SEQ2  (2*SEQ)          // 3072
#define TEMP_INV 20.0f         // 1 / 0.05
// feats stored as fp8 e4m3 pre-scaled by 8 => sim accumulator carries 64x
#define EXP_SCALE (TEMP_INV / 64.0f)   // 0.3125

// GEMM tiling: 128x128, A direct global->reg (L2-resident), B in LDS dbuf
#define BM 128
#define BN 128
#define BK 128                          // fp8 elements per K-tile (128 B/row)
#define KITERS (DIM/BK)                 // 8
#define TILES  (SEQ2 / BM)              // 24
#define NPAIRS (TILES * (TILES+1) / 2)  // 300 upper-triangular tile pairs

typedef int   i32x4 __attribute__((ext_vector_type(4)));
typedef int   i32x8 __attribute__((ext_vector_type(8)));
typedef float f32x4 __attribute__((ext_vector_type(4)));

#define GLOBAL_AS __attribute__((address_space(1)))
#define LDS_AS    __attribute__((address_space(3)))

__device__ inline void async_ld16(const void* g, void* lds_uniform) {
    // gfx950: direct global->LDS, 16B/lane; LDS dest = wave-uniform base + lane*16
    __builtin_amdgcn_global_load_lds((const GLOBAL_AS void*)g, (LDS_AS void*)lds_uniform, 16, 0, 0);
}

__device__ inline float wave_red64(float v) {
    #pragma unroll
    for (int m = 32; m > 0; m >>= 1) v += __shfl_xor(v, m, 64);
    return v;
}

// ---------------------------------------------------------------------------
// Kernel 1: L2-normalize both views -> fp8 e4m3 feats (x8 pre-scale)
// (R4-measured-best form: coalesced 16B/lane loads, per-dword stores.)
// ---------------------------------------------------------------------------
__global__ __launch_bounds__(256) void normalize_kernel(
        const float* __restrict__ h1, const float* __restrict__ h2,
        unsigned char* __restrict__ feats, float* __restrict__ pos_cos,
        float* __restrict__ Ng, float* __restrict__ out) {
    int w = threadIdx.x >> 6, lane = threadIdx.x & 63;
    int tok = blockIdx.x * 4 + w;                 // 0 .. B*S-1
    int b = tok / SEQ, s = tok - b * SEQ;

    const float4* a4 = (const float4*)(h1 + (size_t)tok * DIM);
    const float4* b4 = (const float4*)(h2 + (size_t)tok * DIM);
    float4 av[4], bv[4];
    #pragma unroll
    for (int it = 0; it < 4; it++) { av[it] = a4[lane + 64*it]; bv[it] = b4[lane + 64*it]; }

    float ss1 = 0.f, ss2 = 0.f, sd = 0.f;
    #pragma unroll
    for (int it = 0; it < 4; it++) {
        ss1 += av[it].x*av[it].x + av[it].y*av[it].y + av[it].z*av[it].z + av[it].w*av[it].w;
        ss2 += bv[it].x*bv[it].x + bv[it].y*bv[it].y + bv[it].z*bv[it].z + bv[it].w*bv[it].w;
        sd  += av[it].x*bv[it].x + av[it].y*bv[it].y + av[it].z*bv[it].z + av[it].w*bv[it].w;
    }
    ss1 = wave_red64(ss1); ss2 = wave_red64(ss2); sd = wave_red64(sd);

    float sc1 = 1.0f / fmaxf(sqrtf(ss1), 1e-12f);
    float sc2 = 1.0f / fmaxf(sqrtf(ss2), 1e-12f);
    float s18 = sc1 * 8.0f, s28 = sc2 * 8.0f;   // x8: keep fp8 values normal

    unsigned int* f1row = (unsigned int*)(feats + ((size_t)b * SEQ2 + s) * DIM);
    unsigned int* f2row = (unsigned int*)(feats + ((size_t)b * SEQ2 + SEQ + s) * DIM);
    #pragma unroll
    for (int it = 0; it < 4; it++) {
        int p1 = __builtin_amdgcn_cvt_pk_fp8_f32(av[it].x * s18, av[it].y * s18, 0, 0);
        p1     = __builtin_amdgcn_cvt_pk_fp8_f32(av[it].z * s18, av[it].w * s18, p1, 1);
        int p2 = __builtin_amdgcn_cvt_pk_fp8_f32(bv[it].x * s28, bv[it].y * s28, 0, 0);
        p2     = __builtin_amdgcn_cvt_pk_fp8_f32(bv[it].z * s28, bv[it].w * s28, p2, 1);
        f1row[lane + 64*it] = (unsigned int)p1;
        f2row[lane + 64*it] = (unsigned int)p2;
    }
    if (lane == 0) {
        pos_cos[tok] = sd * sc1 * sc2;
        Ng[2*tok] = 0.0f;
        Ng[2*tok + 1] = 0.0f;
        if (tok == 0) out[0] = 0.0f;   // loss blocks accumulate into out
    }
}

// ---------------------------------------------------------------------------
// Kernel 2: symmetric fused sim-GEMM + exp + neg-mask, MX-fp8 K=128.
// R7 structure: A fragments loaded DIRECTLY global->registers (feats is
// L2-resident per-XCD: 3 MB/batch, batch pinned via bid&7) with the exact
// per-lane MFMA mapping (row ibase+wrow*64+mi*16+(lane&15), bytes
// it*128+(lane>>4)*32 -- bit-identical data to the R4 LDS path).
// B stays LDS-staged, now DOUBLE-buffered (2x16KB+masks = 33.8KB -> still
// 3 blocks/CU), with ONE barrier per K-iter:
//   iter k: A-loads(k) [8 dwordx4] | SB0 | stage B(k+1)->buf[k^1] [4 DMA]
//           | SB0 | ds_read B(k) from buf[k&1] | 16 MFMA
//           | vmcnt(0) [drains stage, which flew across A-wait+ds+MFMA]
//           | s_barrier
// A-use wait is compiler-counted vmcnt(4) (stage is newer in FIFO) so the
// stage stays in flight until the end-of-iter drain.  Cross-wave safety:
// each wave's B ds_reads complete before its barrier (MFMA data-deps force
// the lgkm wait), and each wave drains its own stage before the barrier
// (wait-before-barrier rule).  LDS traffic and DMA volume halved vs R4.
// ---------------------------------------------------------------------------
__global__ __launch_bounds__(256, 3) void gemm_ng_kernel(
        const unsigned char* __restrict__ feats, const int* __restrict__ mask,
        float* __restrict__ Ng) {
    int bid = blockIdx.x;
    int b = bid & 7;                 // XCD-local batch (m09: placement %8); 2400%8==0
    int p = bid >> 3;                // 0..299 triangular pair index
    int ti = 0;
    while (p >= TILES - ti) { p -= TILES - ti; ti++; }
    int tj = ti + p;
    int ibase = ti * BM, jbase = tj * BN;
    bool isdiag = (ti == tj);

    const unsigned char* fb = feats + (size_t)b * SEQ2 * DIM;

    __shared__ __align__(16) unsigned char Bs[2][BN][BK];  // 32 KB dbuf
    __shared__ float mrow_s[BM];
    __shared__ float mcol_s[BN];

    int t = threadIdx.x;
    int lane = t & 63, w = t >> 6;
    int wrow = w >> 1, wcol = w & 1;       // 2x2 waves -> 64x64 each
    int colq = lane & 15, quad = lane >> 4;

    // B staging (R4 swizzle): per issue (4 KB = 32 rows x 128 B), thread t
    // covers row sr = t>>3, slot t&7 -> logical source chunk (t&7) ^ (sr&7).
    int sr = t >> 3;
    int sc = (t & 7) ^ (sr & 7);
    const unsigned char* b0 = fb + (size_t)(jbase + sr) * DIM + sc * 16;

    auto stageB = [&](int it, int d) {
        size_t kb = (size_t)it * BK;
        char* base = (char*)&Bs[d][0][0];
        #pragma unroll
        for (int q = 0; q < 4; q++)       // 32 rows per issue
            async_ld16(b0 + (size_t)q * 32 * DIM + kb, base + q * 4096 + w * 1024);
    };

    stageB(0, 0);                        // first DMA flies during mask setup

    // stage masks (as float) for the tile's rows/cols
    if (t < BM) {
        int i = ibase + t; int im = (i < SEQ) ? i : i - SEQ;
        mrow_s[t] = mask[b * SEQ + im] ? 1.0f : 0.0f;
    } else {
        int j = jbase + (t - BM); int jm = (j < SEQ) ? j : j - SEQ;
        mcol_s[t - BM] = mask[b * SEQ + jm] ? 1.0f : 0.0f;
    }
    __syncthreads();     // vmcnt(0)+lgkm(0)+barrier: B tile 0 + masks resident

    // A global row bases (per-lane, MFMA operand mapping)
    const unsigned char* aG0 = fb + (size_t)(ibase + wrow*64      + colq) * DIM + quad * 32;
    const unsigned char* aG1 = aG0 + (size_t)16 * DIM;
    const unsigned char* aG2 = aG0 + (size_t)32 * DIM;
    const unsigned char* aG3 = aG0 + (size_t)48 * DIM;

    f32x4 acc[4][4] = {};
    // swizzled byte offsets of the two 16B chunks holding k = quad*32..+31
    int s0 = ((2 * quad)     ^ (colq & 7)) * 16;
    int s1 = ((2 * quad + 1) ^ (colq & 7)) * 16;

    #pragma unroll 1
    for (int it = 0; it < KITERS; it++) {
        size_t kb = (size_t)it * BK;
        // 1) A fragments: 8 global dwordx4 (L2 hits; compiler-counted vmcnt)
        i32x4 al0 = *(const i32x4*)(aG0 + kb);
        i32x4 ah0 = *(const i32x4*)(aG0 + kb + 16);
        i32x4 al1 = *(const i32x4*)(aG1 + kb);
        i32x4 ah1 = *(const i32x4*)(aG1 + kb + 16);
        i32x4 al2 = *(const i32x4*)(aG2 + kb);
        i32x4 ah2 = *(const i32x4*)(aG2 + kb + 16);
        i32x4 al3 = *(const i32x4*)(aG3 + kb);
        i32x4 ah3 = *(const i32x4*)(aG3 + kb + 16);
        __builtin_amdgcn_sched_barrier(0);   // A-loads stay OLDER than stage
        // 2) stage next B tile into the other buffer (flies to end of iter)
        if (it + 1 < KITERS) stageB(it + 1, (it + 1) & 1);
        __builtin_amdgcn_sched_barrier(0);   // stage issued before ds_reads
        // 3) B fragments from LDS buf[it&1]
        i32x8 bg[4];
        #pragma unroll
        for (int nj = 0; nj < 4; nj++) {
            int row = wcol * 64 + nj * 16 + colq;   // row&7 == colq&7
            const unsigned char* rp = &Bs[it & 1][row][0];
            i32x4 lo = *(const i32x4*)(rp + s0);
            i32x4 hi = *(const i32x4*)(rp + s1);
            bg[nj] = __builtin_shufflevector(lo, hi, 0, 1, 2, 3, 4, 5, 6, 7);
        }
        i32x8 af0 = __builtin_shufflevector(al0, ah0, 0, 1, 2, 3, 4, 5, 6, 7);
        i32x8 af1 = __builtin_shufflevector(al1, ah1, 0, 1, 2, 3, 4, 5, 6, 7);
        i32x8 af2 = __builtin_shufflevector(al2, ah2, 0, 1, 2, 3, 4, 5, 6, 7);
        i32x8 af3 = __builtin_shufflevector(al3, ah3, 0, 1, 2, 3, 4, 5, 6, 7);
        // 4) MFMAs (compiler waits: vmcnt(4) for A — stage stays in flight —
        //    and counted lgkm for B)
        #pragma unroll
        for (int nj = 0; nj < 4; nj++) {
            acc[0][nj] = __builtin_amdgcn_mfma_scale_f32_16x16x128_f8f6f4(
                af0, bg[nj], acc[0][nj], 0, 0, 0, 0x7F7F7F7F, 0, 0x7F7F7F7F);
            acc[1][nj] = __builtin_amdgcn_mfma_scale_f32_16x16x128_f8f6f4(
                af1, bg[nj], acc[1][nj], 0, 0, 0, 0x7F7F7F7F, 0, 0x7F7F7F7F);
            acc[2][nj] = __builtin_amdgcn_mfma_scale_f32_16x16x128_f8f6f4(
                af2, bg[nj], acc[2][nj], 0, 0, 0, 0x7F7F7F7F, 0, 0x7F7F7F7F);
            acc[3][nj] = __builtin_amdgcn_mfma_scale_f32_16x16x128_f8f6f4(
                af3, bg[nj], acc[3][nj], 0, 0, 0, 0x7F7F7F7F, 0, 0x7F7F7F7F);
        }
        // 5) drain own stage (landed for everyone after the barrier)
        if (it + 1 < KITERS) {
            asm volatile("s_waitcnt vmcnt(0)" ::: "memory");
            __builtin_amdgcn_s_barrier();
        }
    }

    // Epilogue.  C/D layout: col = colq, row = quad*4 + reg.
    float mj[4]; int jglob[4];
    #pragma unroll
    for (int nj = 0; nj < 4; nj++) {
        int jl = wcol * 64 + nj * 16 + colq;
        mj[nj] = mcol_s[jl];
        jglob[nj] = jbase + jl;
    }
    float colsum[4] = {0.f, 0.f, 0.f, 0.f};

    #pragma unroll
    for (int mi = 0; mi < 4; mi++) {
        int il0 = wrow * 64 + mi * 16 + quad * 4;
        float rsum[4] = {0.f, 0.f, 0.f, 0.f};
        float mr[4];
        #pragma unroll
        for (int r = 0; r < 4; r++) mr[r] = mrow_s[il0 + r];
        #pragma unroll
        for (int nj = 0; nj < 4; nj++) {
            #pragma unroll
            for (int r = 0; r < 4; r++) {
                int d = (ibase + il0 + r) - jglob[nj];
                bool same = (d == 0) | (d == SEQ) | (d == -SEQ);
                float e = same ? 0.0f : __expf(acc[mi][nj][r] * EXP_SCALE);
                rsum[r] += e * mj[nj];
                colsum[nj] += e * mr[r];
            }
        }
        // reduce each row sum across the 16 column lanes
        #pragma unroll
        for (int r = 0; r < 4; r++) {
            float v = rsum[r];
            #pragma unroll
            for (int m = 1; m < 16; m <<= 1) v += __shfl_xor(v, m, 64);
            if (colq == 0)
                atomicAdd(&Ng[b * SEQ2 + ibase + il0 + r], v);
        }
    }

    if (!isdiag) {
        // reduce col sums across the 4 quads
        #pragma unroll
        for (int nj = 0; nj < 4; nj++) {
            float v = colsum[nj];
            v += __shfl_xor(v, 16, 64);
            v += __shfl_xor(v, 32, 64);
            if (quad == 0)
                atomicAdd(&Ng[b * SEQ2 + jglob[nj]], v);
        }
    }
}

// ---------------------------------------------------------------------------
// Kernel 3: per-batch masked mean of per-token loss, accumulated straight
// into out[0].  per_tok[i] = log1p(Ng[i] * exp(-pos_sim/T)).
// ---------------------------------------------------------------------------
__global__ __launch_bounds__(1024) void loss_kernel(
        const float* __restrict__ Ng, const float* __restrict__ pos_cos,
        const int* __restrict__ mask, float* __restrict__ out) {
    int b = blockIdx.x, t = threadIdx.x;
    float sum = 0.f, cnt = 0.f;
    for (int i = t; i < SEQ2; i += 1024) {
        int im = (i < SEQ) ? i : i - SEQ;
        if (mask[b * SEQ + im]) {
            float ps = pos_cos[b * SEQ + im] * TEMP_INV;
            float ng = Ng[b * SEQ2 + i];
            sum += log1pf(ng * __expf(-ps));
            cnt += 1.0f;
        }
    }
    sum = wave_red64(sum); cnt = wave_red64(cnt);
    __shared__ float rs[16], rc[16];
    int lane = t & 63, w = t >> 6;
    if (lane == 0) { rs[w] = sum; rc[w] = cnt; }
    __syncthreads();
    if (t == 0) {
        float s = 0.f, c = 0.f;
        #pragma unroll
        for (int k = 0; k < 16; k++) { s += rs[k]; c += rc[k]; }
        atomicAdd(out, s / c * (1.0f / BATCH));
    }
}

// ---------------------------------------------------------------------------
extern "C" void kernel_launch(void* const* d_in, const int* in_sizes, int n_in,
                              void* d_out, int out_size, void* d_ws, size_t ws_size,
                              hipStream_t stream) {
    const float* h1  = (const float*)d_in[0];
    const float* h2  = (const float*)d_in[1];
    const int* mask  = (const int*)d_in[2];
    float* out       = (float*)d_out;

    char* ws = (char*)d_ws;
    size_t feats_bytes = (size_t)BATCH * SEQ2 * DIM;          // 25,165,824 (fp8)
    unsigned char* feats = (unsigned char*)ws;
    float* pos_cos    = (float*)(ws + feats_bytes);
    float* Ng         = (float*)(ws + feats_bytes + (size_t)BATCH * SEQ * 4);

    normalize_kernel<<<BATCH * SEQ / 4, 256, 0, stream>>>(h1, h2, feats, pos_cos, Ng, out);

    gemm_ng_kernel<<<NPAIRS * BATCH, 256, 0, stream>>>(feats, mask, Ng);

    loss_kernel<<<BATCH, 1024, 0, stream>>>(Ng, pos_cos, mask, out);
}

// Round 8
// 199.911 us; speedup vs baseline: 1.1351x; 1.1351x over previous
//
#include <hip/hip_runtime.h>
#include <hip/hip_bf16.h>
#include <math.h>

// Problem constants (from reference setup_inputs)
#define BATCH 8
#define SEQ   1536
#define DIM   1024
#define SEQ2  (2*SEQ)          // 3072
#define TEMP_INV 20.0f         // 1 / 0.05
// feats stored as fp8 e4m3 pre-scaled by 8 => sim accumulator carries 64x
#define EXP_SCALE (TEMP_INV / 64.0f)   // 0.3125

// GEMM tiling: 128x128, A single-buffer + B double-buffer, 3 blocks/CU
#define BM 128
#define BN 128
#define BK 128                          // fp8 elements per K-tile (128 B/row)
#define KITERS (DIM/BK)                 // 8
#define TILES  (SEQ2 / BM)              // 24
#define NPAIRS (TILES * (TILES+1) / 2)  // 300 upper-triangular tile pairs

typedef int   i32x4 __attribute__((ext_vector_type(4)));
typedef int   i32x8 __attribute__((ext_vector_type(8)));
typedef float f32x4 __attribute__((ext_vector_type(4)));

#define GLOBAL_AS __attribute__((address_space(1)))
#define LDS_AS    __attribute__((address_space(3)))

__device__ inline void async_ld16(const void* g, void* lds_uniform) {
    // gfx950: direct global->LDS, 16B/lane; LDS dest = wave-uniform base + lane*16
    __builtin_amdgcn_global_load_lds((const GLOBAL_AS void*)g, (LDS_AS void*)lds_uniform, 16, 0, 0);
}

__device__ inline float wave_red64(float v) {
    #pragma unroll
    for (int m = 32; m > 0; m >>= 1) v += __shfl_xor(v, m, 64);
    return v;
}

// ---------------------------------------------------------------------------
// Kernel 1: L2-normalize both views -> fp8 e4m3 feats (x8 pre-scale)
// (R4-measured-best form: coalesced 16B/lane loads, per-dword stores.)
// ---------------------------------------------------------------------------
__global__ __launch_bounds__(256) void normalize_kernel(
        const float* __restrict__ h1, const float* __restrict__ h2,
        unsigned char* __restrict__ feats, float* __restrict__ pos_cos,
        float* __restrict__ Ng, float* __restrict__ out) {
    int w = threadIdx.x >> 6, lane = threadIdx.x & 63;
    int tok = blockIdx.x * 4 + w;                 // 0 .. B*S-1
    int b = tok / SEQ, s = tok - b * SEQ;

    const float4* a4 = (const float4*)(h1 + (size_t)tok * DIM);
    const float4* b4 = (const float4*)(h2 + (size_t)tok * DIM);
    float4 av[4], bv[4];
    #pragma unroll
    for (int it = 0; it < 4; it++) { av[it] = a4[lane + 64*it]; bv[it] = b4[lane + 64*it]; }

    float ss1 = 0.f, ss2 = 0.f, sd = 0.f;
    #pragma unroll
    for (int it = 0; it < 4; it++) {
        ss1 += av[it].x*av[it].x + av[it].y*av[it].y + av[it].z*av[it].z + av[it].w*av[it].w;
        ss2 += bv[it].x*bv[it].x + bv[it].y*bv[it].y + bv[it].z*bv[it].z + bv[it].w*bv[it].w;
        sd  += av[it].x*bv[it].x + av[it].y*bv[it].y + av[it].z*bv[it].z + av[it].w*bv[it].w;
    }
    ss1 = wave_red64(ss1); ss2 = wave_red64(ss2); sd = wave_red64(sd);

    float sc1 = 1.0f / fmaxf(sqrtf(ss1), 1e-12f);
    float sc2 = 1.0f / fmaxf(sqrtf(ss2), 1e-12f);
    float s18 = sc1 * 8.0f, s28 = sc2 * 8.0f;   // x8: keep fp8 values normal

    unsigned int* f1row = (unsigned int*)(feats + ((size_t)b * SEQ2 + s) * DIM);
    unsigned int* f2row = (unsigned int*)(feats + ((size_t)b * SEQ2 + SEQ + s) * DIM);
    #pragma unroll
    for (int it = 0; it < 4; it++) {
        int p1 = __builtin_amdgcn_cvt_pk_fp8_f32(av[it].x * s18, av[it].y * s18, 0, 0);
        p1     = __builtin_amdgcn_cvt_pk_fp8_f32(av[it].z * s18, av[it].w * s18, p1, 1);
        int p2 = __builtin_amdgcn_cvt_pk_fp8_f32(bv[it].x * s28, bv[it].y * s28, 0, 0);
        p2     = __builtin_amdgcn_cvt_pk_fp8_f32(bv[it].z * s28, bv[it].w * s28, p2, 1);
        f1row[lane + 64*it] = (unsigned int)p1;
        f2row[lane + 64*it] = (unsigned int)p2;
    }
    if (lane == 0) {
        pos_cos[tok] = sd * sc1 * sc2;
        Ng[2*tok] = 0.0f;
        Ng[2*tok + 1] = 0.0f;
        if (tok == 0) out[0] = 0.0f;   // loss blocks accumulate into out
    }
}

// ---------------------------------------------------------------------------
// Kernel 2: symmetric fused sim-GEMM + exp + neg-mask, MX-fp8 K=128.
// R8 structure: R4's proven geometry (128x128, 4 waves, coalesced
// global_load_lds staging, zero-conflict XOR swizzle) with As SINGLE-buffer
// (16 KB) + Bs DOUBLE-buffer (2x16 KB) = 49 KB -> still 3 blocks/CU, and
// RAW barriers with COUNTED waits instead of __syncthreads (whose mandatory
// vmcnt(0) drain killed the prefetch window):
//   iter it: ds_read A-frags(As) + B-frags(Bs[it&1])
//            -> lgkmcnt(0); s_barrier          [reads done; B(it+1) STAYS in flight]
//            -> stage A(it+1)->As, B(it+2)->Bs[it&1]
//            -> sched_barrier(0) -> 16 MFMA
//            -> vmcnt(4); s_barrier            [A(it+1),B(it+1) landed; B(it+2) flies on]
// B staging gets a FULL-ITERATION flight window; A keeps the MFMA window.
// vmcnt ledger: steady-state outstanding at tail = B(it+1)[4]+A(it+1)[4]+
// B(it+2)[4]=12 -> vmcnt(4); it==6: 8 -> vmcnt(0); it==7: none.
// Overwrite hazard closed by barrier #1 (all waves' lgkm drained before any
// wave issues the stage).
// ---------------------------------------------------------------------------
__global__ __launch_bounds__(256, 3) void gemm_ng_kernel(
        const unsigned char* __restrict__ feats, const int* __restrict__ mask,
        float* __restrict__ Ng) {
    int bid = blockIdx.x;
    int b = bid & 7;                 // XCD-local batch (m09: placement %8); 2400%8==0
    int p = bid >> 3;                // 0..299 triangular pair index
    int ti = 0;
    while (p >= TILES - ti) { p -= TILES - ti; ti++; }
    int tj = ti + p;
    int ibase = ti * BM, jbase = tj * BN;
    bool isdiag = (ti == tj);

    const unsigned char* fb = feats + (size_t)b * SEQ2 * DIM;

    __shared__ __align__(16) unsigned char As[BM][BK];     // 16 KB single
    __shared__ __align__(16) unsigned char Bs[2][BN][BK];  // 32 KB dbuf
    __shared__ float mrow_s[BM];
    __shared__ float mcol_s[BN];

    int t = threadIdx.x;
    int lane = t & 63, w = t >> 6;
    int wrow = w >> 1, wcol = w & 1;       // 2x2 waves -> 64x64 each
    int colq = lane & 15, quad = lane >> 4;

    // Staging: per issue (4 KB = 32 rows x 128 B), thread t covers row
    // sr = t>>3, stored slot t&7 -> logical source chunk (t&7) ^ (sr&7).
    int sr = t >> 3;
    int sc = (t & 7) ^ (sr & 7);
    const unsigned char* a0 = fb + (size_t)(ibase + sr) * DIM + sc * 16;
    const unsigned char* b0 = fb + (size_t)(jbase + sr) * DIM + sc * 16;

    auto stageA = [&](int it) {
        size_t kb = (size_t)it * BK;
        #pragma unroll
        for (int q = 0; q < 4; q++)       // 32 rows per issue
            async_ld16(a0 + (size_t)q * 32 * DIM + kb, (char*)&As[0][0] + q * 4096 + w * 1024);
    };
    auto stageB = [&](int it, int d) {
        size_t kb = (size_t)it * BK;
        #pragma unroll
        for (int q = 0; q < 4; q++)
            async_ld16(b0 + (size_t)q * 32 * DIM + kb, (char*)&Bs[d][0][0] + q * 4096 + w * 1024);
    };

    // Prologue: B(0), A(0), B(1) issued (12 loads); masks while they fly.
    stageB(0, 0);
    stageA(0);
    stageB(1, 1);

    if (t < BM) {
        int i = ibase + t; int im = (i < SEQ) ? i : i - SEQ;
        mrow_s[t] = mask[b * SEQ + im] ? 1.0f : 0.0f;
    } else {
        int j = jbase + (t - BM); int jm = (j < SEQ) ? j : j - SEQ;
        mcol_s[t - BM] = mask[b * SEQ + jm] ? 1.0f : 0.0f;
    }
    // Drain B(0)+A(0) (oldest 8) + mask LDS writes; B(1) stays in flight.
    asm volatile("s_waitcnt vmcnt(4) lgkmcnt(0)" ::: "memory");
    __builtin_amdgcn_s_barrier();

    f32x4 acc[4][4] = {};
    // swizzled byte offsets of the two 16B chunks holding k = quad*32..+31
    int s0 = ((2 * quad)     ^ (colq & 7)) * 16;
    int s1 = ((2 * quad + 1) ^ (colq & 7)) * 16;

    #pragma unroll 1
    for (int it = 0; it < KITERS; it++) {
        i32x8 af[4], bg[4];
        #pragma unroll
        for (int mi = 0; mi < 4; mi++) {
            int row = wrow * 64 + mi * 16 + colq;   // row&7 == colq&7
            i32x4 lo = *(const i32x4*)&As[row][s0];
            i32x4 hi = *(const i32x4*)&As[row][s1];
            af[mi] = __builtin_shufflevector(lo, hi, 0, 1, 2, 3, 4, 5, 6, 7);
        }
        #pragma unroll
        for (int nj = 0; nj < 4; nj++) {
            int row = wcol * 64 + nj * 16 + colq;
            const unsigned char* rp = &Bs[it & 1][row][0];
            i32x4 lo = *(const i32x4*)(rp + s0);
            i32x4 hi = *(const i32x4*)(rp + s1);
            bg[nj] = __builtin_shufflevector(lo, hi, 0, 1, 2, 3, 4, 5, 6, 7);
        }

        // All waves' frag reads complete; does NOT drain vmem (B(it+1) flies).
        asm volatile("s_waitcnt lgkmcnt(0)" ::: "memory");
        __builtin_amdgcn_s_barrier();

        if (it + 1 < KITERS) stageA(it + 1);            // window: MFMA stretch
        if (it + 2 < KITERS) stageB(it + 2, it & 1);    // window: full next iter
        __builtin_amdgcn_sched_barrier(0);              // MFMAs stay below

        #pragma unroll
        for (int mi = 0; mi < 4; mi++)
            #pragma unroll
            for (int nj = 0; nj < 4; nj++)
                acc[mi][nj] = __builtin_amdgcn_mfma_scale_f32_16x16x128_f8f6f4(
                    af[mi], bg[nj], acc[mi][nj],
                    0, 0,                       // cbsz=fp8, blgp=fp8
                    0, 0x7F7F7F7F,              // opselA, scaleA = 2^0
                    0, 0x7F7F7F7F);             // opselB, scaleB = 2^0

        if (it + 1 < KITERS) {
            // outstanding: B(it+1)[4] + A(it+1)[4] (+ B(it+2)[4] if staged)
            if (it + 2 < KITERS)
                asm volatile("s_waitcnt vmcnt(4)" ::: "memory");
            else
                asm volatile("s_waitcnt vmcnt(0)" ::: "memory");
            __builtin_amdgcn_s_barrier();
        }
    }

    // Epilogue.  C/D layout: col = colq, row = quad*4 + reg.
    float mj[4]; int jglob[4];
    #pragma unroll
    for (int nj = 0; nj < 4; nj++) {
        int jl = wcol * 64 + nj * 16 + colq;
        mj[nj] = mcol_s[jl];
        jglob[nj] = jbase + jl;
    }
    float colsum[4] = {0.f, 0.f, 0.f, 0.f};

    #pragma unroll
    for (int mi = 0; mi < 4; mi++) {
        int il0 = wrow * 64 + mi * 16 + quad * 4;
        float rsum[4] = {0.f, 0.f, 0.f, 0.f};
        float mr[4];
        #pragma unroll
        for (int r = 0; r < 4; r++) mr[r] = mrow_s[il0 + r];
        #pragma unroll
        for (int nj = 0; nj < 4; nj++) {
            #pragma unroll
            for (int r = 0; r < 4; r++) {
                int d = (ibase + il0 + r) - jglob[nj];
                bool same = (d == 0) | (d == SEQ) | (d == -SEQ);
                float e = same ? 0.0f : __expf(acc[mi][nj][r] * EXP_SCALE);
                rsum[r] += e * mj[nj];
                colsum[nj] += e * mr[r];
            }
        }
        // reduce each row sum across the 16 column lanes
        #pragma unroll
        for (int r = 0; r < 4; r++) {
            float v = rsum[r];
            #pragma unroll
            for (int m = 1; m < 16; m <<= 1) v += __shfl_xor(v, m, 64);
            if (colq == 0)
                atomicAdd(&Ng[b * SEQ2 + ibase + il0 + r], v);
        }
    }

    if (!isdiag) {
        // reduce col sums across the 4 quads
        #pragma unroll
        for (int nj = 0; nj < 4; nj++) {
            float v = colsum[nj];
            v += __shfl_xor(v, 16, 64);
            v += __shfl_xor(v, 32, 64);
            if (quad == 0)
                atomicAdd(&Ng[b * SEQ2 + jglob[nj]], v);
        }
    }
}

// ---------------------------------------------------------------------------
// Kernel 3: per-batch masked mean of per-token loss, accumulated straight
// into out[0].  per_tok[i] = log1p(Ng[i] * exp(-pos_sim/T)).
// ---------------------------------------------------------------------------
__global__ __launch_bounds__(1024) void loss_kernel(
        const float* __restrict__ Ng, const float* __restrict__ pos_cos,
        const int* __restrict__ mask, float* __restrict__ out) {
    int b = blockIdx.x, t = threadIdx.x;
    float sum = 0.f, cnt = 0.f;
    for (int i = t; i < SEQ2; i += 1024) {
        int im = (i < SEQ) ? i : i - SEQ;
        if (mask[b * SEQ + im]) {
            float ps = pos_cos[b * SEQ + im] * TEMP_INV;
            float ng = Ng[b * SEQ2 + i];
            sum += log1pf(ng * __expf(-ps));
            cnt += 1.0f;
        }
    }
    sum = wave_red64(sum); cnt = wave_red64(cnt);
    __shared__ float rs[16], rc[16];
    int lane = t & 63, w = t >> 6;
    if (lane == 0) { rs[w] = sum; rc[w] = cnt; }
    __syncthreads();
    if (t == 0) {
        float s = 0.f, c = 0.f;
        #pragma unroll
        for (int k = 0; k < 16; k++) { s += rs[k]; c += rc[k]; }
        atomicAdd(out, s / c * (1.0f / BATCH));
    }
}

// ---------------------------------------------------------------------------
extern "C" void kernel_launch(void* const* d_in, const int* in_sizes, int n_in,
                              void* d_out, int out_size, void* d_ws, size_t ws_size,
                              hipStream_t stream) {
    const float* h1  = (const float*)d_in[0];
    const float* h2  = (const float*)d_in[1];
    const int* mask  = (const int*)d_in[2];
    float* out       = (float*)d_out;

    char* ws = (char*)d_ws;
    size_t feats_bytes = (size_t)BATCH * SEQ2 * DIM;          // 25,165,824 (fp8)
    unsigned char* feats = (unsigned char*)ws;
    float* pos_cos    = (float*)(ws + feats_bytes);
    float* Ng         = (float*)(ws + feats_bytes + (size_t)BATCH * SEQ * 4);

    normalize_kernel<<<BATCH * SEQ / 4, 256, 0, stream>>>(h1, h2, feats, pos_cos, Ng, out);

    gemm_ng_kernel<<<NPAIRS * BATCH, 256, 0, stream>>>(feats, mask, Ng);

    loss_kernel<<<BATCH, 1024, 0, stream>>>(Ng, pos_cos, mask, out);
}